// Round 10
// baseline (433.857 us; speedup 1.0000x reference)
//
#include <hip/hip_runtime.h>
#include <math.h>

#define N_USER 100000
#define N_ITEM 50000
#define N_EDGE 800000
#define D_IN 256
#define D_H 128
#define HEADS 4

typedef __attribute__((ext_vector_type(8))) short short8v;   // 8 bf16 (4 VGPR)
typedef __attribute__((ext_vector_type(4))) float f32x4;     // 4 fp32

__device__ __forceinline__ unsigned short f2bf(float x) {    // RNE f32->bf16
  unsigned u = __float_as_uint(x);
  return (unsigned short)((u + 0x7FFFu + ((u >> 16) & 1u)) >> 16);
}
__device__ __forceinline__ float bf2f(unsigned short h) {
  return __uint_as_float((unsigned)h << 16);
}
__device__ __forceinline__ f32x4 splat4(float x) { return (f32x4){x, x, x, x}; }

// ---------------------------------------------------------------------------
// CSR row offsets, edge-parallel run writes (each rs[i] written exactly once).
// ---------------------------------------------------------------------------
__global__ void row_offsets_kernel(const int* __restrict__ dst, int n_edge,
                                   int* __restrict__ rs, int n_dst) {
  int e = blockIdx.x * blockDim.x + threadIdx.x;
  if (e >= n_edge) return;
  int d = dst[e];
  int dprev = (e == 0) ? -1 : dst[e - 1];
  for (int i = dprev + 1; i <= d; ++i) rs[i] = e;
  if (e == n_edge - 1)
    for (int i = d + 1; i <= n_dst; ++i) rs[i] = n_edge;
}

// ---------------------------------------------------------------------------
// One-time W prep: W[256][128] fp32 -> Wt_hi/Wt_lo[128][256] bf16, k permuted
// to the MFMA fragment slot order: slot (kb=lane>>4, j) holds
// k = kb*4 + (j&3) + 16*(j>>2); stored at [n][kbase + kb*8 + j].
// ---------------------------------------------------------------------------
__global__ __launch_bounds__(256) void wt_prep_kernel(
    const float* __restrict__ W, unsigned short* __restrict__ WtHi,
    unsigned short* __restrict__ WtLo) {
  int tid = blockIdx.x * blockDim.x + threadIdx.x;
  if (tid >= D_IN * D_H) return;
  int n = tid & 127, k = tid >> 7;
  float x = W[(size_t)k * D_H + n];
  unsigned short h = f2bf(x);
  unsigned short l = f2bf(x - bf2f(h));
  int kk = k & 31, kbase = k & ~31;
  int pos = (kk < 16) ? ((kk >> 2) * 8 + (kk & 3))
                      : (((kk - 16) >> 2) * 8 + 4 + (kk & 3));
  WtHi[(size_t)n * D_IN + kbase + pos] = h;
  WtLo[(size_t)n * D_IN + kbase + pos] = l;
}

// ---------------------------------------------------------------------------
// FUSED projections: C = A @ W + bias for BOTH user and item in ONE dispatch
// (2345 blocks vs 782 -- r9 diagnosis: GEMM was wave-starved, 3 blocks/CU,
// occupancy 23%, all pipes ~90% idle while each wave stalls on memory).
// M-tile 64, wave owns 16 rows (1 m-frag x 8 n-frags, acc=32 VGPR) -> 2x
// blocks, half-weight waves. A tile (64x64 fp32 = 16KB) via global_load_lds
// w=16, XOR-swizzled through the global source address (m104/m173). B frags
// direct from L2 (slot-ordered Wt). Split-bf16 via TRUNCATION (hi=top16,
// lo=top16 of remainder): ~4 VALU/elem vs 8, err <= 2^-16 rel.
// C/D layout (verified m89): col = lane&15, row = (lane>>4)*4 + reg.
// ---------------------------------------------------------------------------
__global__ __launch_bounds__(256, 4) void gemm_fused_kernel(
    const float* __restrict__ Au, const float* __restrict__ Ai,
    const unsigned short* __restrict__ WtUHi, const unsigned short* __restrict__ WtULo,
    const unsigned short* __restrict__ WtIHi, const unsigned short* __restrict__ WtILo,
    const float* __restrict__ bu, const float* __restrict__ bi,
    float* __restrict__ Cu, float* __restrict__ Ci, int nbu) {
  __shared__ float Atile[64 * 64];                     // 16 KB
  const bool isU = (int)blockIdx.x < nbu;
  const float* A = isU ? Au : Ai;
  const unsigned short* WtHi = isU ? WtUHi : WtIHi;
  const unsigned short* WtLo = isU ? WtULo : WtILo;
  const float* bias = isU ? bu : bi;
  float* C = isU ? Cu : Ci;
  const int M = isU ? N_USER : N_ITEM;
  const int m0 = (isU ? (int)blockIdx.x : (int)blockIdx.x - nbu) * 64;

  const int t = threadIdx.x;
  const int wave = t >> 6, lane = t & 63;
  const int l15 = lane & 15, kb = lane >> 4;
  const unsigned short* bh_base = WtHi + (size_t)l15 * D_IN + kb * 8;
  const unsigned short* bl_base = WtLo + (size_t)l15 * D_IN + kb * 8;

  f32x4 acc[8];
#pragma unroll
  for (int nf = 0; nf < 8; ++nf) acc[nf] = (f32x4){0.f, 0.f, 0.f, 0.f};

  for (int k0 = 0; k0 < D_IN; k0 += 64) {
    // ---- stage A tile 64x64 fp32 via global_load_lds (4 instrs/wave) ----
#pragma unroll
    for (int i = 0; i < 4; ++i) {
      int rloc = wave * 16 + i * 4 + (lane >> 4);      // tile row this lane feeds
      int gr = m0 + rloc; if (gr >= M) gr = M - 1;     // clamp (rows never stored)
      int u = (lane & 15) ^ (rloc & 7);                // pre-swizzled 16B unit
      const float* src = A + (size_t)gr * D_IN + k0 + u * 4;
      char* dstb = (char*)Atile + (size_t)(wave * 16 + i * 4) * 256;  // uniform
      __builtin_amdgcn_global_load_lds(
          (const __attribute__((address_space(1))) unsigned int*)src,
          (__attribute__((address_space(3))) unsigned int*)dstb, 16, 0, 0);
    }
    __syncthreads();

    // ---- compute: 2 k-frags of 32 ----
#pragma unroll
    for (int kf = 0; kf < 2; ++kf) {
      const int row = wave * 16 + l15;
      const int u0 = (kf * 8 + kb) ^ (row & 7);        // slots j=0..3
      const int u1 = u0 ^ 4;                           // slots j=4..7 (+16 in k)
      float4 f0 = *(const float4*)((const char*)Atile + (size_t)row * 256 + u0 * 16);
      float4 f1 = *(const float4*)((const char*)Atile + (size_t)row * 256 + u1 * 16);
      short8v ah, al;
      {
        const float e[8] = {f0.x, f0.y, f0.z, f0.w, f1.x, f1.y, f1.z, f1.w};
#pragma unroll
        for (int j = 0; j < 8; ++j) {
          unsigned u32 = __float_as_uint(e[j]);
          unsigned short h = (unsigned short)(u32 >> 16);   // trunc hi
          ah[j] = (short)h;
          float d = e[j] - bf2f(h);
          al[j] = (short)(__float_as_uint(d) >> 16);        // trunc lo
        }
      }
      const int kk = k0 + kf * 32;
#pragma unroll
      for (int nf = 0; nf < 8; ++nf) {
        short8v bh = *(const short8v*)(bh_base + (size_t)nf * 16 * D_IN + kk);
        short8v bl = *(const short8v*)(bl_base + (size_t)nf * 16 * D_IN + kk);
        acc[nf] = __builtin_amdgcn_mfma_f32_16x16x32_bf16(ah, bh, acc[nf], 0, 0, 0);
        acc[nf] = __builtin_amdgcn_mfma_f32_16x16x32_bf16(ah, bl, acc[nf], 0, 0, 0);
        acc[nf] = __builtin_amdgcn_mfma_f32_16x16x32_bf16(al, bh, acc[nf], 0, 0, 0);
      }
    }
    __syncthreads();
  }

  // ---- epilogue ----
#pragma unroll
  for (int nf = 0; nf < 8; ++nf) {
    float bv = bias[nf * 16 + l15];
#pragma unroll
    for (int r = 0; r < 4; ++r) {
      int grow = m0 + wave * 16 + kb * 4 + r;
      if (grow < M) C[(size_t)grow * D_H + nf * 16 + l15] = acc[nf][r] + bv;
    }
  }
}

// ---------------------------------------------------------------------------
// s[n,4] = C[n,128] @ a[4,128]^T  (one wave per row; optional second a)
// ---------------------------------------------------------------------------
__global__ __launch_bounds__(256) void scores_kernel(
    const float* __restrict__ C, int n,
    const float* __restrict__ a0, float* __restrict__ s0,
    const float* __restrict__ a1, float* __restrict__ s1) {
  int wid = (blockIdx.x * blockDim.x + threadIdx.x) >> 6;
  int lane = threadIdx.x & 63;
  if (wid >= n) return;
  float2 v = *(const float2*)&C[(size_t)wid * D_H + lane * 2];
#pragma unroll
  for (int h = 0; h < HEADS; ++h) {
    float p = v.x * a0[h * D_H + lane * 2] + v.y * a0[h * D_H + lane * 2 + 1];
#pragma unroll
    for (int off = 32; off; off >>= 1) p += __shfl_xor(p, off);
    if (lane == 0) s0[wid * HEADS + h] = p;
  }
  if (a1) {
#pragma unroll
    for (int h = 0; h < HEADS; ++h) {
      float p = v.x * a1[h * D_H + lane * 2] + v.y * a1[h * D_H + lane * 2 + 1];
#pragma unroll
      for (int off = 32; off; off >>= 1) p += __shfl_xor(p, off);
      if (lane == 0) s1[wid * HEADS + h] = p;
    }
  }
}

// ---------------------------------------------------------------------------
// Per-edge UNNORMALIZED weights w = exp(leaky_relu(s_src+s_dst)).
// ---------------------------------------------------------------------------
__global__ __launch_bounds__(256) void edge_w_kernel(
    const float* __restrict__ s_src, const float* __restrict__ s_dst,
    const int* __restrict__ src_idx, const int* __restrict__ dst_idx,
    float* __restrict__ wout, int n_edge) {
  int e = blockIdx.x * blockDim.x + threadIdx.x;
  if (e >= n_edge) return;
  int s = src_idx[e], d = dst_idx[e];
  f32x4 a = *(const f32x4*)&s_src[(size_t)s * HEADS];
  f32x4 b = *(const f32x4*)&s_dst[(size_t)d * HEADS];
  f32x4 v = a + b;
  v.x = (v.x >= 0.f) ? v.x : 0.2f * v.x;
  v.y = (v.y >= 0.f) ? v.y : 0.2f * v.y;
  v.z = (v.z >= 0.f) ? v.z : 0.2f * v.z;
  v.w = (v.w >= 0.f) ? v.w : 0.2f * v.w;
  f32x4 w = {__expf(v.x), __expf(v.y), __expf(v.z), __expf(v.w)};
  *(f32x4*)&wout[(size_t)e * HEADS] = w;
}

// ---------------------------------------------------------------------------
// Weighted gather-sum + in-loop denominator. One wave per dst;
// lanes = 2 edge-slots x 32 dim-groups (float4). Packed f32x4 math.
// Epilogue: rcp (not div); ELU split across half-waves.
// ---------------------------------------------------------------------------
__global__ __launch_bounds__(256) void attend_sum_kernel(
    const float* __restrict__ h_src, const float* __restrict__ w4,
    const int* __restrict__ src_idx, const int* __restrict__ rs,
    float* __restrict__ out, int n_dst,
    const float* __restrict__ a_next, float* __restrict__ s_out) {
  int wid = (blockIdx.x * blockDim.x + threadIdx.x) >> 6;
  int lane = threadIdx.x & 63;
  if (wid >= n_dst) return;
  const int el = lane >> 5;
  const int dl = lane & 31;
  int e0 = rs[wid], e1 = rs[wid + 1];

  f32x4 acc0 = {0, 0, 0, 0}, acc1 = acc0, acc2 = acc0, acc3 = acc0;
  f32x4 den = {0, 0, 0, 0};

  int base = e0;
  for (; base + 4 <= e1; base += 4) {
    int eA = base + el, eB = base + 2 + el;
    int sA = src_idx[eA], sB = src_idx[eB];
    f32x4 hA = *(const f32x4*)&h_src[(size_t)sA * D_H + dl * 4];
    f32x4 hB = *(const f32x4*)&h_src[(size_t)sB * D_H + dl * 4];
    f32x4 wA = *(const f32x4*)&w4[(size_t)eA * HEADS];
    f32x4 wB = *(const f32x4*)&w4[(size_t)eB * HEADS];
    den += wA; den += wB;
    acc0 = __builtin_elementwise_fma(splat4(wA.x), hA, acc0);
    acc1 = __builtin_elementwise_fma(splat4(wA.y), hA, acc1);
    acc2 = __builtin_elementwise_fma(splat4(wA.z), hA, acc2);
    acc3 = __builtin_elementwise_fma(splat4(wA.w), hA, acc3);
    acc0 = __builtin_elementwise_fma(splat4(wB.x), hB, acc0);
    acc1 = __builtin_elementwise_fma(splat4(wB.y), hB, acc1);
    acc2 = __builtin_elementwise_fma(splat4(wB.z), hB, acc2);
    acc3 = __builtin_elementwise_fma(splat4(wB.w), hB, acc3);
  }
  for (; base < e1; base += 2) {
    int e = base + el;
    bool valid = e < e1;
    int ec = valid ? e : e1 - 1;
    int s = src_idx[ec];
    f32x4 hv = *(const f32x4*)&h_src[(size_t)s * D_H + dl * 4];
    f32x4 wv = *(const f32x4*)&w4[(size_t)ec * HEADS];
    if (!valid) wv = (f32x4){0, 0, 0, 0};
    den += wv;
    acc0 = __builtin_elementwise_fma(splat4(wv.x), hv, acc0);
    acc1 = __builtin_elementwise_fma(splat4(wv.y), hv, acc1);
    acc2 = __builtin_elementwise_fma(splat4(wv.z), hv, acc2);
    acc3 = __builtin_elementwise_fma(splat4(wv.w), hv, acc3);
  }

#define MRG(a) \
  a.x += __shfl_xor(a.x, 32); a.y += __shfl_xor(a.y, 32); \
  a.z += __shfl_xor(a.z, 32); a.w += __shfl_xor(a.w, 32);
  MRG(acc0) MRG(acc1) MRG(acc2) MRG(acc3) MRG(den)
#undef MRG

  float rA = den.x > 0.f ? __builtin_amdgcn_rcpf(den.x) : 0.f;
  float rB = den.y > 0.f ? __builtin_amdgcn_rcpf(den.y) : 0.f;
  float rC = den.z > 0.f ? __builtin_amdgcn_rcpf(den.z) : 0.f;
  float rD = den.w > 0.f ? __builtin_amdgcn_rcpf(den.w) : 0.f;

  f32x4 p = el ? acc2 : acc0;
  f32x4 q = el ? acc3 : acc1;
  float rp = el ? rC : rA;
  float rq = el ? rD : rB;
  p *= splat4(rp); q *= splat4(rq);
#define ELU4(a) \
  a.x = (a.x > 0.f) ? a.x : (__expf(a.x) - 1.f); \
  a.y = (a.y > 0.f) ? a.y : (__expf(a.y) - 1.f); \
  a.z = (a.z > 0.f) ? a.z : (__expf(a.z) - 1.f); \
  a.w = (a.w > 0.f) ? a.w : (__expf(a.w) - 1.f);
  ELU4(p) ELU4(q)
#undef ELU4
  f32x4 s4 = p + q;
  s4.x += __shfl_xor(s4.x, 32);
  s4.y += __shfl_xor(s4.y, 32);
  s4.z += __shfl_xor(s4.z, 32);
  s4.w += __shfl_xor(s4.w, 32);
  f32x4 o = s4 * splat4(0.25f);

  if (el == 0) *(f32x4*)&out[(size_t)wid * D_H + dl * 4] = o;

  if (s_out) {
#pragma unroll
    for (int h = 0; h < HEADS; ++h) {
      const float* ah = &a_next[h * D_H + dl * 4];
      float p2 = o.x * ah[0] + o.y * ah[1] + o.z * ah[2] + o.w * ah[3];
#pragma unroll
      for (int off = 16; off; off >>= 1) p2 += __shfl_xor(p2, off);
      if (lane == 0) s_out[wid * HEADS + h] = p2;
    }
  }
}

// ---------------------------------------------------------------------------
extern "C" void kernel_launch(void* const* d_in, const int* in_sizes, int n_in,
                              void* d_out, int out_size, void* d_ws, size_t ws_size,
                              hipStream_t stream) {
  const float* h_user     = (const float*)d_in[0];
  const float* h_item     = (const float*)d_in[1];
  const float* w_user     = (const float*)d_in[2];
  const float* b_user     = (const float*)d_in[3];
  const float* w_item     = (const float*)d_in[4];
  const float* b_item     = (const float*)d_in[5];
  const float* a_user_src = (const float*)d_in[6];
  const float* a_user_dst = (const float*)d_in[7];
  const float* a_item_src = (const float*)d_in[8];
  const float* a_item_dst = (const float*)d_in[9];
  const int* i2u_src = (const int*)d_in[10];
  const int* i2u_dst = (const int*)d_in[11];
  const int* u2i_src = (const int*)d_in[12];
  const int* u2i_dst = (const int*)d_in[13];

  float* out_user = (float*)d_out;                       // hu_new (N_USER,128)
  float* out_item = out_user + (size_t)N_USER * D_H;     // hi_new (N_ITEM,128)

  // workspace layout
  float* hu      = (float*)d_ws;                         // (N_USER,128) 51.2MB
  float* hi      = hu + (size_t)N_USER * D_H;            // (N_ITEM,128)
  float* s_i_src = hi + (size_t)N_ITEM * D_H;            // (N_ITEM,4)
  float* s_i_dst = s_i_src + (size_t)N_ITEM * HEADS;     // (N_ITEM,4)
  float* s_u_dst = s_i_dst + (size_t)N_ITEM * HEADS;     // (N_USER,4)
  float* s_un    = s_u_dst + (size_t)N_USER * HEADS;     // (N_USER,4)
  int* user_rs = (int*)(s_un + (size_t)N_USER * HEADS);  // N_USER+1
  int* item_rs = user_rs + (N_USER + 1);                 // N_ITEM+1
  unsigned short* wtu_hi = (unsigned short*)
      (((uintptr_t)(item_rs + N_ITEM + 1) + 15) & ~(uintptr_t)15);
  unsigned short* wtu_lo = wtu_hi + (size_t)D_IN * D_H;
  unsigned short* wti_hi = wtu_lo + (size_t)D_IN * D_H;
  unsigned short* wti_lo = wti_hi + (size_t)D_IN * D_H;
  // hu is dead after scores_kernel -> alias edge weight buffer into it
  float* wbuf = hu;                                      // (E,4) 12.8MB

  // CSR offsets (edge-parallel run writes)
  hipLaunchKernelGGL(row_offsets_kernel, dim3((N_EDGE + 255) / 256), dim3(256), 0,
                     stream, i2u_dst, N_EDGE, user_rs, N_USER);
  hipLaunchKernelGGL(row_offsets_kernel, dim3((N_EDGE + 255) / 256), dim3(256), 0,
                     stream, u2i_dst, N_EDGE, item_rs, N_ITEM);

  // W prep + FUSED projections (one dispatch, 2345 blocks)
  hipLaunchKernelGGL(wt_prep_kernel, dim3(D_IN * D_H / 256), dim3(256), 0, stream,
                     w_user, wtu_hi, wtu_lo);
  hipLaunchKernelGGL(wt_prep_kernel, dim3(D_IN * D_H / 256), dim3(256), 0, stream,
                     w_item, wti_hi, wti_lo);
  const int nbu = (N_USER + 63) / 64;                    // 1563
  const int nbi = (N_ITEM + 63) / 64;                    // 782
  hipLaunchKernelGGL(gemm_fused_kernel, dim3(nbu + nbi), dim3(256), 0, stream,
                     h_user, h_item, wtu_hi, wtu_lo, wti_hi, wti_lo,
                     b_user, b_item, hu, hi, nbu);

  // per-node attention scores
  hipLaunchKernelGGL(scores_kernel, dim3(N_ITEM / 4), dim3(256), 0, stream,
                     hi, N_ITEM, a_user_src, s_i_src, a_item_dst, s_i_dst);
  hipLaunchKernelGGL(scores_kernel, dim3(N_USER / 4), dim3(256), 0, stream,
                     hu, N_USER, a_user_dst, s_u_dst, (const float*)nullptr, (float*)nullptr);

  // ---- layer 1: items -> users ----
  hipLaunchKernelGGL(edge_w_kernel, dim3((N_EDGE + 255) / 256), dim3(256), 0, stream,
                     s_i_src, s_u_dst, i2u_src, i2u_dst, wbuf, N_EDGE);
  hipLaunchKernelGGL(attend_sum_kernel, dim3((N_USER + 3) / 4), dim3(256), 0, stream,
                     hi, wbuf, i2u_src, user_rs, out_user, N_USER,
                     a_item_src, s_un);

  // ---- layer 2: updated users -> items ----
  hipLaunchKernelGGL(edge_w_kernel, dim3((N_EDGE + 255) / 256), dim3(256), 0, stream,
                     s_un, s_i_dst, u2i_src, u2i_dst, wbuf, N_EDGE);
  hipLaunchKernelGGL(attend_sum_kernel, dim3((N_ITEM + 3) / 4), dim3(256), 0, stream,
                     out_user, wbuf, u2i_src, item_rs, out_item, N_ITEM,
                     (const float*)nullptr, (float*)nullptr);
}

// Round 11
// 348.844 us; speedup vs baseline: 1.2437x; 1.2437x over previous
//
#include <hip/hip_runtime.h>
#include <math.h>

#define N_USER 100000
#define N_ITEM 50000
#define N_EDGE 800000
#define D_IN 256
#define D_H 128
#define HEADS 4

typedef __attribute__((ext_vector_type(8))) short short8v;   // 8 bf16 (4 VGPR)
typedef __attribute__((ext_vector_type(4))) float f32x4;     // 4 fp32

__device__ __forceinline__ unsigned short f2bf(float x) {    // RNE f32->bf16
  unsigned u = __float_as_uint(x);
  return (unsigned short)((u + 0x7FFFu + ((u >> 16) & 1u)) >> 16);
}
__device__ __forceinline__ float bf2f(unsigned short h) {
  return __uint_as_float((unsigned)h << 16);
}
__device__ __forceinline__ f32x4 splat4(float x) { return (f32x4){x, x, x, x}; }

// ---------------------------------------------------------------------------
// CSR row offsets, edge-parallel run writes (each rs[i] written exactly once).
// ---------------------------------------------------------------------------
__global__ void row_offsets_kernel(const int* __restrict__ dst, int n_edge,
                                   int* __restrict__ rs, int n_dst) {
  int e = blockIdx.x * blockDim.x + threadIdx.x;
  if (e >= n_edge) return;
  int d = dst[e];
  int dprev = (e == 0) ? -1 : dst[e - 1];
  for (int i = dprev + 1; i <= d; ++i) rs[i] = e;
  if (e == n_edge - 1)
    for (int i = d + 1; i <= n_dst; ++i) rs[i] = n_edge;
}

// ---------------------------------------------------------------------------
// One-time W prep (RNE split): W[256][128] fp32 -> Wt_hi/Wt_lo[128][256] bf16,
// k permuted to MFMA slot order: pos(k) s.t. slot (kb,j) holds
// k = kb*4 + (j&3) + 16*(j>>2).
// ---------------------------------------------------------------------------
__global__ __launch_bounds__(256) void wt_prep_kernel(
    const float* __restrict__ W, unsigned short* __restrict__ WtHi,
    unsigned short* __restrict__ WtLo) {
  int tid = blockIdx.x * blockDim.x + threadIdx.x;
  if (tid >= D_IN * D_H) return;
  int n = tid & 127, k = tid >> 7;
  float x = W[(size_t)k * D_H + n];
  unsigned short h = f2bf(x);
  unsigned short l = f2bf(x - bf2f(h));
  int kk = k & 31, kbase = k & ~31;
  int pos = (kk < 16) ? ((kk >> 2) * 8 + (kk & 3))
                      : (((kk - 16) >> 2) * 8 + 4 + (kk & 3));
  WtHi[(size_t)n * D_IN + kbase + pos] = h;
  WtLo[(size_t)n * D_IN + kbase + pos] = l;
}

// ---------------------------------------------------------------------------
// FUSED projections, r5-measured-best structure (96+48 us as two dispatches):
// LDS-staged split-bf16 MFMA (Ah*Wh + Ah*Wl + Al*Wh, fp32 accumulate).
// Block: 256 thr = 4 waves; tile 128 rows x 128 cols; BK=32.
// Both A and B tiles staged in LDS; ds_read_b128 feeds MFMA (the only
// operand path measured to beat latency here; direct-from-global variants
// r6/r8/r9/r10 all stall ~95% on un-pipelined L2/HBM loads).
// Single dispatch covers user (blocks < nbu) and item (rest) tiles.
// C/D layout (verified m89): col = lane&15, row = (lane>>4)*4 + reg.
// ---------------------------------------------------------------------------
__global__ __launch_bounds__(256) void gemm_fused_kernel(
    const float* __restrict__ Au, const float* __restrict__ Ai,
    const unsigned short* __restrict__ WtUHi, const unsigned short* __restrict__ WtULo,
    const unsigned short* __restrict__ WtIHi, const unsigned short* __restrict__ WtILo,
    const float* __restrict__ bu, const float* __restrict__ bi,
    float* __restrict__ Cu, float* __restrict__ Ci, int nbu) {
  __shared__ unsigned short Ah[128][32], Al[128][32];   // 8KB + 8KB
  __shared__ unsigned short Bh[128][32], Bl[128][32];   // 8KB + 8KB
  const bool isU = (int)blockIdx.x < nbu;
  const float* A = isU ? Au : Ai;
  const unsigned short* WtHi = isU ? WtUHi : WtIHi;
  const unsigned short* WtLo = isU ? WtULo : WtILo;
  const float* bias = isU ? bu : bi;
  float* C = isU ? Cu : Ci;
  const int M = isU ? N_USER : N_ITEM;
  const int m0 = (isU ? (int)blockIdx.x : (int)blockIdx.x - nbu) * 128;

  const int t = threadIdx.x;
  const int wave = t >> 6, lane = t & 63;
  const int l15 = lane & 15, kb = lane >> 4;

  f32x4 acc[2][8];
#pragma unroll
  for (int mf = 0; mf < 2; ++mf)
#pragma unroll
    for (int nf = 0; nf < 8; ++nf) acc[mf][nf] = (f32x4){0.f, 0.f, 0.f, 0.f};

  for (int k0 = 0; k0 < D_IN; k0 += 32) {
    // stage A tile 128x32 fp32 -> hi/lo bf16, k permuted to slot order
#pragma unroll
    for (int i = 0; i < 4; ++i) {
      int idx = t + i * 256;             // 0..1023
      int row = idx >> 3, c = idx & 7;   // float4 chunk c: k-offset 4c
      float4 av = make_float4(0.f, 0.f, 0.f, 0.f);
      if (m0 + row < M) av = *(const float4*)&A[(size_t)(m0 + row) * D_IN + k0 + c * 4];
      ushort4 hv, lv;
      hv.x = f2bf(av.x); lv.x = f2bf(av.x - bf2f(hv.x));
      hv.y = f2bf(av.y); lv.y = f2bf(av.y - bf2f(hv.y));
      hv.z = f2bf(av.z); lv.z = f2bf(av.z - bf2f(hv.z));
      hv.w = f2bf(av.w); lv.w = f2bf(av.w - bf2f(hv.w));
      int base = (c < 4) ? c * 8 : (c - 4) * 8 + 4;   // slot-order position
      *(ushort4*)&Ah[row][base] = hv;
      *(ushort4*)&Al[row][base] = lv;
    }
    // stage B tile: Wt already transposed+slot-permuted -> straight 16B copies
#pragma unroll
    for (int i = 0; i < 2; ++i) {
      int idx = t + i * 256;             // 0..511
      int row = idx >> 2, ch = idx & 3;  // 4 x 16B per row (32 bf16)
      *(uint4*)&Bh[row][ch * 8] = *(const uint4*)&WtHi[(size_t)row * D_IN + k0 + ch * 8];
      *(uint4*)&Bl[row][ch * 8] = *(const uint4*)&WtLo[(size_t)row * D_IN + k0 + ch * 8];
    }
    __syncthreads();

    short8v ah[2], al[2];
#pragma unroll
    for (int mf = 0; mf < 2; ++mf) {
      ah[mf] = *(const short8v*)&Ah[wave * 32 + mf * 16 + l15][kb * 8];
      al[mf] = *(const short8v*)&Al[wave * 32 + mf * 16 + l15][kb * 8];
    }
#pragma unroll
    for (int nf = 0; nf < 8; ++nf) {
      short8v bh = *(const short8v*)&Bh[nf * 16 + l15][kb * 8];
      short8v bl = *(const short8v*)&Bl[nf * 16 + l15][kb * 8];
#pragma unroll
      for (int mf = 0; mf < 2; ++mf) {
        acc[mf][nf] = __builtin_amdgcn_mfma_f32_16x16x32_bf16(ah[mf], bh, acc[mf][nf], 0, 0, 0);
        acc[mf][nf] = __builtin_amdgcn_mfma_f32_16x16x32_bf16(ah[mf], bl, acc[mf][nf], 0, 0, 0);
        acc[mf][nf] = __builtin_amdgcn_mfma_f32_16x16x32_bf16(al[mf], bh, acc[mf][nf], 0, 0, 0);
      }
    }
    __syncthreads();
  }

#pragma unroll
  for (int nf = 0; nf < 8; ++nf) {
    float bv = bias[nf * 16 + l15];
#pragma unroll
    for (int mf = 0; mf < 2; ++mf) {
#pragma unroll
      for (int r = 0; r < 4; ++r) {
        int grow = m0 + wave * 32 + mf * 16 + kb * 4 + r;
        if (grow < M) C[(size_t)grow * D_H + nf * 16 + l15] = acc[mf][nf][r] + bv;
      }
    }
  }
}

// ---------------------------------------------------------------------------
// s[n,4] = C[n,128] @ a[4,128]^T  (one wave per row; optional second a)
// ---------------------------------------------------------------------------
__global__ __launch_bounds__(256) void scores_kernel(
    const float* __restrict__ C, int n,
    const float* __restrict__ a0, float* __restrict__ s0,
    const float* __restrict__ a1, float* __restrict__ s1) {
  int wid = (blockIdx.x * blockDim.x + threadIdx.x) >> 6;
  int lane = threadIdx.x & 63;
  if (wid >= n) return;
  float2 v = *(const float2*)&C[(size_t)wid * D_H + lane * 2];
#pragma unroll
  for (int h = 0; h < HEADS; ++h) {
    float p = v.x * a0[h * D_H + lane * 2] + v.y * a0[h * D_H + lane * 2 + 1];
#pragma unroll
    for (int off = 32; off; off >>= 1) p += __shfl_xor(p, off);
    if (lane == 0) s0[wid * HEADS + h] = p;
  }
  if (a1) {
#pragma unroll
    for (int h = 0; h < HEADS; ++h) {
      float p = v.x * a1[h * D_H + lane * 2] + v.y * a1[h * D_H + lane * 2 + 1];
#pragma unroll
      for (int off = 32; off; off >>= 1) p += __shfl_xor(p, off);
      if (lane == 0) s1[wid * HEADS + h] = p;
    }
  }
}

// ---------------------------------------------------------------------------
// Per-edge UNNORMALIZED weights w = exp(leaky_relu(s_src+s_dst)).
// ---------------------------------------------------------------------------
__global__ __launch_bounds__(256) void edge_w_kernel(
    const float* __restrict__ s_src, const float* __restrict__ s_dst,
    const int* __restrict__ src_idx, const int* __restrict__ dst_idx,
    float* __restrict__ wout, int n_edge) {
  int e = blockIdx.x * blockDim.x + threadIdx.x;
  if (e >= n_edge) return;
  int s = src_idx[e], d = dst_idx[e];
  f32x4 a = *(const f32x4*)&s_src[(size_t)s * HEADS];
  f32x4 b = *(const f32x4*)&s_dst[(size_t)d * HEADS];
  f32x4 v = a + b;
  v.x = (v.x >= 0.f) ? v.x : 0.2f * v.x;
  v.y = (v.y >= 0.f) ? v.y : 0.2f * v.y;
  v.z = (v.z >= 0.f) ? v.z : 0.2f * v.z;
  v.w = (v.w >= 0.f) ? v.w : 0.2f * v.w;
  f32x4 w = {__expf(v.x), __expf(v.y), __expf(v.z), __expf(v.w)};
  *(f32x4*)&wout[(size_t)e * HEADS] = w;
}

// ---------------------------------------------------------------------------
// Weighted gather-sum + in-loop denominator. One wave per dst;
// lanes = 2 edge-slots x 32 dim-groups (float4). Packed f32x4 math.
// Epilogue: rcp (not div); ELU split across half-waves.
// ---------------------------------------------------------------------------
__global__ __launch_bounds__(256) void attend_sum_kernel(
    const float* __restrict__ h_src, const float* __restrict__ w4,
    const int* __restrict__ src_idx, const int* __restrict__ rs,
    float* __restrict__ out, int n_dst,
    const float* __restrict__ a_next, float* __restrict__ s_out) {
  int wid = (blockIdx.x * blockDim.x + threadIdx.x) >> 6;
  int lane = threadIdx.x & 63;
  if (wid >= n_dst) return;
  const int el = lane >> 5;
  const int dl = lane & 31;
  int e0 = rs[wid], e1 = rs[wid + 1];

  f32x4 acc0 = {0, 0, 0, 0}, acc1 = acc0, acc2 = acc0, acc3 = acc0;
  f32x4 den = {0, 0, 0, 0};

  int base = e0;
  for (; base + 4 <= e1; base += 4) {
    int eA = base + el, eB = base + 2 + el;
    int sA = src_idx[eA], sB = src_idx[eB];
    f32x4 hA = *(const f32x4*)&h_src[(size_t)sA * D_H + dl * 4];
    f32x4 hB = *(const f32x4*)&h_src[(size_t)sB * D_H + dl * 4];
    f32x4 wA = *(const f32x4*)&w4[(size_t)eA * HEADS];
    f32x4 wB = *(const f32x4*)&w4[(size_t)eB * HEADS];
    den += wA; den += wB;
    acc0 = __builtin_elementwise_fma(splat4(wA.x), hA, acc0);
    acc1 = __builtin_elementwise_fma(splat4(wA.y), hA, acc1);
    acc2 = __builtin_elementwise_fma(splat4(wA.z), hA, acc2);
    acc3 = __builtin_elementwise_fma(splat4(wA.w), hA, acc3);
    acc0 = __builtin_elementwise_fma(splat4(wB.x), hB, acc0);
    acc1 = __builtin_elementwise_fma(splat4(wB.y), hB, acc1);
    acc2 = __builtin_elementwise_fma(splat4(wB.z), hB, acc2);
    acc3 = __builtin_elementwise_fma(splat4(wB.w), hB, acc3);
  }
  for (; base < e1; base += 2) {
    int e = base + el;
    bool valid = e < e1;
    int ec = valid ? e : e1 - 1;
    int s = src_idx[ec];
    f32x4 hv = *(const f32x4*)&h_src[(size_t)s * D_H + dl * 4];
    f32x4 wv = *(const f32x4*)&w4[(size_t)ec * HEADS];
    if (!valid) wv = (f32x4){0, 0, 0, 0};
    den += wv;
    acc0 = __builtin_elementwise_fma(splat4(wv.x), hv, acc0);
    acc1 = __builtin_elementwise_fma(splat4(wv.y), hv, acc1);
    acc2 = __builtin_elementwise_fma(splat4(wv.z), hv, acc2);
    acc3 = __builtin_elementwise_fma(splat4(wv.w), hv, acc3);
  }

#define MRG(a) \
  a.x += __shfl_xor(a.x, 32); a.y += __shfl_xor(a.y, 32); \
  a.z += __shfl_xor(a.z, 32); a.w += __shfl_xor(a.w, 32);
  MRG(acc0) MRG(acc1) MRG(acc2) MRG(acc3) MRG(den)
#undef MRG

  float rA = den.x > 0.f ? __builtin_amdgcn_rcpf(den.x) : 0.f;
  float rB = den.y > 0.f ? __builtin_amdgcn_rcpf(den.y) : 0.f;
  float rC = den.z > 0.f ? __builtin_amdgcn_rcpf(den.z) : 0.f;
  float rD = den.w > 0.f ? __builtin_amdgcn_rcpf(den.w) : 0.f;

  f32x4 p = el ? acc2 : acc0;
  f32x4 q = el ? acc3 : acc1;
  float rp = el ? rC : rA;
  float rq = el ? rD : rB;
  p *= splat4(rp); q *= splat4(rq);
#define ELU4(a) \
  a.x = (a.x > 0.f) ? a.x : (__expf(a.x) - 1.f); \
  a.y = (a.y > 0.f) ? a.y : (__expf(a.y) - 1.f); \
  a.z = (a.z > 0.f) ? a.z : (__expf(a.z) - 1.f); \
  a.w = (a.w > 0.f) ? a.w : (__expf(a.w) - 1.f);
  ELU4(p) ELU4(q)
#undef ELU4
  f32x4 s4 = p + q;
  s4.x += __shfl_xor(s4.x, 32);
  s4.y += __shfl_xor(s4.y, 32);
  s4.z += __shfl_xor(s4.z, 32);
  s4.w += __shfl_xor(s4.w, 32);
  f32x4 o = s4 * splat4(0.25f);

  if (el == 0) *(f32x4*)&out[(size_t)wid * D_H + dl * 4] = o;

  if (s_out) {
#pragma unroll
    for (int h = 0; h < HEADS; ++h) {
      const float* ah = &a_next[h * D_H + dl * 4];
      float p2 = o.x * ah[0] + o.y * ah[1] + o.z * ah[2] + o.w * ah[3];
#pragma unroll
      for (int off = 16; off; off >>= 1) p2 += __shfl_xor(p2, off);
      if (lane == 0) s_out[wid * HEADS + h] = p2;
    }
  }
}

// ---------------------------------------------------------------------------
extern "C" void kernel_launch(void* const* d_in, const int* in_sizes, int n_in,
                              void* d_out, int out_size, void* d_ws, size_t ws_size,
                              hipStream_t stream) {
  const float* h_user     = (const float*)d_in[0];
  const float* h_item     = (const float*)d_in[1];
  const float* w_user     = (const float*)d_in[2];
  const float* b_user     = (const float*)d_in[3];
  const float* w_item     = (const float*)d_in[4];
  const float* b_item     = (const float*)d_in[5];
  const float* a_user_src = (const float*)d_in[6];
  const float* a_user_dst = (const float*)d_in[7];
  const float* a_item_src = (const float*)d_in[8];
  const float* a_item_dst = (const float*)d_in[9];
  const int* i2u_src = (const int*)d_in[10];
  const int* i2u_dst = (const int*)d_in[11];
  const int* u2i_src = (const int*)d_in[12];
  const int* u2i_dst = (const int*)d_in[13];

  float* out_user = (float*)d_out;                       // hu_new (N_USER,128)
  float* out_item = out_user + (size_t)N_USER * D_H;     // hi_new (N_ITEM,128)

  // workspace layout
  float* hu      = (float*)d_ws;                         // (N_USER,128) 51.2MB
  float* hi      = hu + (size_t)N_USER * D_H;            // (N_ITEM,128)
  float* s_i_src = hi + (size_t)N_ITEM * D_H;            // (N_ITEM,4)
  float* s_i_dst = s_i_src + (size_t)N_ITEM * HEADS;     // (N_ITEM,4)
  float* s_u_dst = s_i_dst + (size_t)N_ITEM * HEADS;     // (N_USER,4)
  float* s_un    = s_u_dst + (size_t)N_USER * HEADS;     // (N_USER,4)
  int* user_rs = (int*)(s_un + (size_t)N_USER * HEADS);  // N_USER+1
  int* item_rs = user_rs + (N_USER + 1);                 // N_ITEM+1
  unsigned short* wtu_hi = (unsigned short*)
      (((uintptr_t)(item_rs + N_ITEM + 1) + 15) & ~(uintptr_t)15);
  unsigned short* wtu_lo = wtu_hi + (size_t)D_IN * D_H;
  unsigned short* wti_hi = wtu_lo + (size_t)D_IN * D_H;
  unsigned short* wti_lo = wti_hi + (size_t)D_IN * D_H;
  // hu is dead after scores_kernel -> alias edge weight buffer into it
  float* wbuf = hu;                                      // (E,4) 12.8MB

  // CSR offsets (edge-parallel run writes)
  hipLaunchKernelGGL(row_offsets_kernel, dim3((N_EDGE + 255) / 256), dim3(256), 0,
                     stream, i2u_dst, N_EDGE, user_rs, N_USER);
  hipLaunchKernelGGL(row_offsets_kernel, dim3((N_EDGE + 255) / 256), dim3(256), 0,
                     stream, u2i_dst, N_EDGE, item_rs, N_ITEM);

  // W prep + FUSED projections (r5-best structure, one dispatch, 1173 blocks)
  hipLaunchKernelGGL(wt_prep_kernel, dim3(D_IN * D_H / 256), dim3(256), 0, stream,
                     w_user, wtu_hi, wtu_lo);
  hipLaunchKernelGGL(wt_prep_kernel, dim3(D_IN * D_H / 256), dim3(256), 0, stream,
                     w_item, wti_hi, wti_lo);
  const int nbu = (N_USER + 127) / 128;                  // 782
  const int nbi = (N_ITEM + 127) / 128;                  // 391
  hipLaunchKernelGGL(gemm_fused_kernel, dim3(nbu + nbi), dim3(256), 0, stream,
                     h_user, h_item, wtu_hi, wtu_lo, wti_hi, wti_lo,
                     b_user, b_item, hu, hi, nbu);

  // per-node attention scores
  hipLaunchKernelGGL(scores_kernel, dim3(N_ITEM / 4), dim3(256), 0, stream,
                     hi, N_ITEM, a_user_src, s_i_src, a_item_dst, s_i_dst);
  hipLaunchKernelGGL(scores_kernel, dim3(N_USER / 4), dim3(256), 0, stream,
                     hu, N_USER, a_user_dst, s_u_dst, (const float*)nullptr, (float*)nullptr);

  // ---- layer 1: items -> users ----
  hipLaunchKernelGGL(edge_w_kernel, dim3((N_EDGE + 255) / 256), dim3(256), 0, stream,
                     s_i_src, s_u_dst, i2u_src, i2u_dst, wbuf, N_EDGE);
  hipLaunchKernelGGL(attend_sum_kernel, dim3((N_USER + 3) / 4), dim3(256), 0, stream,
                     hi, wbuf, i2u_src, user_rs, out_user, N_USER,
                     a_item_src, s_un);

  // ---- layer 2: updated users -> items ----
  hipLaunchKernelGGL(edge_w_kernel, dim3((N_EDGE + 255) / 256), dim3(256), 0, stream,
                     s_un, s_i_dst, u2i_src, u2i_dst, wbuf, N_EDGE);
  hipLaunchKernelGGL(attend_sum_kernel, dim3((N_ITEM + 3) / 4), dim3(256), 0, stream,
                     out_user, wbuf, u2i_src, item_rs, out_item, N_ITEM,
                     (const float*)nullptr, (float*)nullptr);
}

// Round 12
// 327.109 us; speedup vs baseline: 1.3263x; 1.0664x over previous
//
#include <hip/hip_runtime.h>
#include <math.h>

#define N_USER 100000
#define N_ITEM 50000
#define N_EDGE 800000
#define D_IN 256
#define D_H 128
#define HEADS 4

typedef __attribute__((ext_vector_type(8))) short short8v;   // 8 bf16 (4 VGPR)
typedef __attribute__((ext_vector_type(4))) float f32x4;     // 4 fp32

__device__ __forceinline__ unsigned short f2bf(float x) {    // RNE f32->bf16
  unsigned u = __float_as_uint(x);
  return (unsigned short)((u + 0x7FFFu + ((u >> 16) & 1u)) >> 16);
}
__device__ __forceinline__ float bf2f(unsigned short h) {
  return __uint_as_float((unsigned)h << 16);
}
__device__ __forceinline__ f32x4 splat4(float x) { return (f32x4){x, x, x, x}; }

// ---------------------------------------------------------------------------
// CSR row offsets, edge-parallel run writes (each rs[i] written exactly once).
// ---------------------------------------------------------------------------
__global__ void row_offsets_kernel(const int* __restrict__ dst, int n_edge,
                                   int* __restrict__ rs, int n_dst) {
  int e = blockIdx.x * blockDim.x + threadIdx.x;
  if (e >= n_edge) return;
  int d = dst[e];
  int dprev = (e == 0) ? -1 : dst[e - 1];
  for (int i = dprev + 1; i <= d; ++i) rs[i] = e;
  if (e == n_edge - 1)
    for (int i = d + 1; i <= n_dst; ++i) rs[i] = n_edge;
}

// ---------------------------------------------------------------------------
// One-time W prep (RNE split): W[256][128] fp32 -> Wt_hi/Wt_lo[128][256] bf16,
// k permuted to MFMA slot order: pos(k) s.t. slot (kb,j) holds
// k = kb*4 + (j&3) + 16*(j>>2).
// ---------------------------------------------------------------------------
__global__ __launch_bounds__(256) void wt_prep_kernel(
    const float* __restrict__ W, unsigned short* __restrict__ WtHi,
    unsigned short* __restrict__ WtLo) {
  int tid = blockIdx.x * blockDim.x + threadIdx.x;
  if (tid >= D_IN * D_H) return;
  int n = tid & 127, k = tid >> 7;
  float x = W[(size_t)k * D_H + n];
  unsigned short h = f2bf(x);
  unsigned short l = f2bf(x - bf2f(h));
  int kk = k & 31, kbase = k & ~31;
  int pos = (kk < 16) ? ((kk >> 2) * 8 + (kk & 3))
                      : (((kk - 16) >> 2) * 8 + 4 + (kk & 3));
  WtHi[(size_t)n * D_IN + kbase + pos] = h;
  WtLo[(size_t)n * D_IN + kbase + pos] = l;
}

// ---------------------------------------------------------------------------
// FUSED projections. r11 structure with ONE change: the A tile is staged via
// global_load_lds (DMA -> no dest VGPRs, compiler cannot serialize
// load->waitcnt->use; the r6/r8 failure mode). A stored fp32 in LDS
// ([128 rows][8 x 16B units], unit ^= row&7 swizzle applied via the GLOBAL
// source address, m104/m173); bf16 hi/lo split moved to the consumer side
// where it overlaps MFMA. B tile staging + all fragment/MFMA/epilogue code
// identical to r11 (measured best: 140us fused).
// C/D layout (verified m89): col = lane&15, row = (lane>>4)*4 + reg.
// ---------------------------------------------------------------------------
__global__ __launch_bounds__(256) void gemm_fused_kernel(
    const float* __restrict__ Au, const float* __restrict__ Ai,
    const unsigned short* __restrict__ WtUHi, const unsigned short* __restrict__ WtULo,
    const unsigned short* __restrict__ WtIHi, const unsigned short* __restrict__ WtILo,
    const float* __restrict__ bu, const float* __restrict__ bi,
    float* __restrict__ Cu, float* __restrict__ Ci, int nbu) {
  __shared__ float Af[128 * 32];                        // fp32 A tile, 16KB
  __shared__ unsigned short Bh[128][32], Bl[128][32];   // 8KB + 8KB
  const bool isU = (int)blockIdx.x < nbu;
  const float* A = isU ? Au : Ai;
  const unsigned short* WtHi = isU ? WtUHi : WtIHi;
  const unsigned short* WtLo = isU ? WtULo : WtILo;
  const float* bias = isU ? bu : bi;
  float* C = isU ? Cu : Ci;
  const int M = isU ? N_USER : N_ITEM;
  const int m0 = (isU ? (int)blockIdx.x : (int)blockIdx.x - nbu) * 128;

  const int t = threadIdx.x;
  const int wave = t >> 6, lane = t & 63;
  const int l15 = lane & 15, kb = lane >> 4;

  f32x4 acc[2][8];
#pragma unroll
  for (int mf = 0; mf < 2; ++mf)
#pragma unroll
    for (int nf = 0; nf < 8; ++nf) acc[mf][nf] = (f32x4){0.f, 0.f, 0.f, 0.f};

  for (int k0 = 0; k0 < D_IN; k0 += 32) {
    // ---- stage A tile 128x32 fp32 via global_load_lds (4 instrs/thread) ----
    // wave fills rows wave*32..wave*32+31; per i: 64 lanes x 16B = 8 rows.
    // HW writes lane l at (uniform base) + l*16 -> row base+ (l>>3), unit l&7.
    // Source pre-swizzled: unit_src = (lane&7) ^ (rloc&7).
#pragma unroll
    for (int i = 0; i < 4; ++i) {
      int rloc = wave * 32 + i * 8 + (lane >> 3);
      int gr = m0 + rloc; if (gr >= M) gr = M - 1;     // clamp; rows never stored
      int u = (lane & 7) ^ (rloc & 7);
      const float* src = A + (size_t)gr * D_IN + k0 + u * 4;
      char* dstb = (char*)Af + (size_t)(wave * 32 + i * 8) * 128;  // wave-uniform
      __builtin_amdgcn_global_load_lds(
          (const __attribute__((address_space(1))) unsigned int*)src,
          (__attribute__((address_space(3))) unsigned int*)dstb, 16, 0, 0);
    }
    // ---- stage B tile (r11 path: 2 x 16B L2-resident copies per thread) ----
#pragma unroll
    for (int i = 0; i < 2; ++i) {
      int idx = t + i * 256;             // 0..511
      int row = idx >> 2, ch = idx & 3;  // 4 x 16B per row (32 bf16)
      *(uint4*)&Bh[row][ch * 8] = *(const uint4*)&WtHi[(size_t)row * D_IN + k0 + ch * 8];
      *(uint4*)&Bl[row][ch * 8] = *(const uint4*)&WtLo[(size_t)row * D_IN + k0 + ch * 8];
    }
    __syncthreads();

    // ---- A fragments: ds_read fp32 (swizzled) -> split to bf16 hi/lo ----
    short8v ah[2], al[2];
#pragma unroll
    for (int mf = 0; mf < 2; ++mf) {
      int row = wave * 32 + mf * 16 + l15;
      int u0 = kb ^ (row & 7);                  // slots j=0..3: k = kb*4+j
      int u1 = (kb + 4) ^ (row & 7);            // slots j=4..7: k = 16+kb*4+j-4
      float4 f0 = *(const float4*)((const char*)Af + (size_t)row * 128 + u0 * 16);
      float4 f1 = *(const float4*)((const char*)Af + (size_t)row * 128 + u1 * 16);
      const float e[8] = {f0.x, f0.y, f0.z, f0.w, f1.x, f1.y, f1.z, f1.w};
#pragma unroll
      for (int j = 0; j < 8; ++j) {
        unsigned short h = f2bf(e[j]);
        ah[mf][j] = (short)h;
        al[mf][j] = (short)f2bf(e[j] - bf2f(h));
      }
    }
#pragma unroll
    for (int nf = 0; nf < 8; ++nf) {
      short8v bh = *(const short8v*)&Bh[nf * 16 + l15][kb * 8];
      short8v bl = *(const short8v*)&Bl[nf * 16 + l15][kb * 8];
#pragma unroll
      for (int mf = 0; mf < 2; ++mf) {
        acc[mf][nf] = __builtin_amdgcn_mfma_f32_16x16x32_bf16(ah[mf], bh, acc[mf][nf], 0, 0, 0);
        acc[mf][nf] = __builtin_amdgcn_mfma_f32_16x16x32_bf16(ah[mf], bl, acc[mf][nf], 0, 0, 0);
        acc[mf][nf] = __builtin_amdgcn_mfma_f32_16x16x32_bf16(al[mf], bh, acc[mf][nf], 0, 0, 0);
      }
    }
    __syncthreads();
  }

#pragma unroll
  for (int nf = 0; nf < 8; ++nf) {
    float bv = bias[nf * 16 + l15];
#pragma unroll
    for (int mf = 0; mf < 2; ++mf) {
#pragma unroll
      for (int r = 0; r < 4; ++r) {
        int grow = m0 + wave * 32 + mf * 16 + kb * 4 + r;
        if (grow < M) C[(size_t)grow * D_H + nf * 16 + l15] = acc[mf][nf][r] + bv;
      }
    }
  }
}

// ---------------------------------------------------------------------------
// s[n,4] = C[n,128] @ a[4,128]^T  (one wave per row; optional second a)
// ---------------------------------------------------------------------------
__global__ __launch_bounds__(256) void scores_kernel(
    const float* __restrict__ C, int n,
    const float* __restrict__ a0, float* __restrict__ s0,
    const float* __restrict__ a1, float* __restrict__ s1) {
  int wid = (blockIdx.x * blockDim.x + threadIdx.x) >> 6;
  int lane = threadIdx.x & 63;
  if (wid >= n) return;
  float2 v = *(const float2*)&C[(size_t)wid * D_H + lane * 2];
#pragma unroll
  for (int h = 0; h < HEADS; ++h) {
    float p = v.x * a0[h * D_H + lane * 2] + v.y * a0[h * D_H + lane * 2 + 1];
#pragma unroll
    for (int off = 32; off; off >>= 1) p += __shfl_xor(p, off);
    if (lane == 0) s0[wid * HEADS + h] = p;
  }
  if (a1) {
#pragma unroll
    for (int h = 0; h < HEADS; ++h) {
      float p = v.x * a1[h * D_H + lane * 2] + v.y * a1[h * D_H + lane * 2 + 1];
#pragma unroll
      for (int off = 32; off; off >>= 1) p += __shfl_xor(p, off);
      if (lane == 0) s1[wid * HEADS + h] = p;
    }
  }
}

// ---------------------------------------------------------------------------
// Per-edge UNNORMALIZED weights w = exp(leaky_relu(s_src+s_dst)).
// ---------------------------------------------------------------------------
__global__ __launch_bounds__(256) void edge_w_kernel(
    const float* __restrict__ s_src, const float* __restrict__ s_dst,
    const int* __restrict__ src_idx, const int* __restrict__ dst_idx,
    float* __restrict__ wout, int n_edge) {
  int e = blockIdx.x * blockDim.x + threadIdx.x;
  if (e >= n_edge) return;
  int s = src_idx[e], d = dst_idx[e];
  f32x4 a = *(const f32x4*)&s_src[(size_t)s * HEADS];
  f32x4 b = *(const f32x4*)&s_dst[(size_t)d * HEADS];
  f32x4 v = a + b;
  v.x = (v.x >= 0.f) ? v.x : 0.2f * v.x;
  v.y = (v.y >= 0.f) ? v.y : 0.2f * v.y;
  v.z = (v.z >= 0.f) ? v.z : 0.2f * v.z;
  v.w = (v.w >= 0.f) ? v.w : 0.2f * v.w;
  f32x4 w = {__expf(v.x), __expf(v.y), __expf(v.z), __expf(v.w)};
  *(f32x4*)&wout[(size_t)e * HEADS] = w;
}

// ---------------------------------------------------------------------------
// Weighted gather-sum + in-loop denominator. One wave per dst;
// lanes = 2 edge-slots x 32 dim-groups (float4). Packed f32x4 math.
// Epilogue: rcp (not div); ELU split across half-waves.
// ---------------------------------------------------------------------------
__global__ __launch_bounds__(256) void attend_sum_kernel(
    const float* __restrict__ h_src, const float* __restrict__ w4,
    const int* __restrict__ src_idx, const int* __restrict__ rs,
    float* __restrict__ out, int n_dst,
    const float* __restrict__ a_next, float* __restrict__ s_out) {
  int wid = (blockIdx.x * blockDim.x + threadIdx.x) >> 6;
  int lane = threadIdx.x & 63;
  if (wid >= n_dst) return;
  const int el = lane >> 5;
  const int dl = lane & 31;
  int e0 = rs[wid], e1 = rs[wid + 1];

  f32x4 acc0 = {0, 0, 0, 0}, acc1 = acc0, acc2 = acc0, acc3 = acc0;
  f32x4 den = {0, 0, 0, 0};

  int base = e0;
  for (; base + 4 <= e1; base += 4) {
    int eA = base + el, eB = base + 2 + el;
    int sA = src_idx[eA], sB = src_idx[eB];
    f32x4 hA = *(const f32x4*)&h_src[(size_t)sA * D_H + dl * 4];
    f32x4 hB = *(const f32x4*)&h_src[(size_t)sB * D_H + dl * 4];
    f32x4 wA = *(const f32x4*)&w4[(size_t)eA * HEADS];
    f32x4 wB = *(const f32x4*)&w4[(size_t)eB * HEADS];
    den += wA; den += wB;
    acc0 = __builtin_elementwise_fma(splat4(wA.x), hA, acc0);
    acc1 = __builtin_elementwise_fma(splat4(wA.y), hA, acc1);
    acc2 = __builtin_elementwise_fma(splat4(wA.z), hA, acc2);
    acc3 = __builtin_elementwise_fma(splat4(wA.w), hA, acc3);
    acc0 = __builtin_elementwise_fma(splat4(wB.x), hB, acc0);
    acc1 = __builtin_elementwise_fma(splat4(wB.y), hB, acc1);
    acc2 = __builtin_elementwise_fma(splat4(wB.z), hB, acc2);
    acc3 = __builtin_elementwise_fma(splat4(wB.w), hB, acc3);
  }
  for (; base < e1; base += 2) {
    int e = base + el;
    bool valid = e < e1;
    int ec = valid ? e : e1 - 1;
    int s = src_idx[ec];
    f32x4 hv = *(const f32x4*)&h_src[(size_t)s * D_H + dl * 4];
    f32x4 wv = *(const f32x4*)&w4[(size_t)ec * HEADS];
    if (!valid) wv = (f32x4){0, 0, 0, 0};
    den += wv;
    acc0 = __builtin_elementwise_fma(splat4(wv.x), hv, acc0);
    acc1 = __builtin_elementwise_fma(splat4(wv.y), hv, acc1);
    acc2 = __builtin_elementwise_fma(splat4(wv.z), hv, acc2);
    acc3 = __builtin_elementwise_fma(splat4(wv.w), hv, acc3);
  }

#define MRG(a) \
  a.x += __shfl_xor(a.x, 32); a.y += __shfl_xor(a.y, 32); \
  a.z += __shfl_xor(a.z, 32); a.w += __shfl_xor(a.w, 32);
  MRG(acc0) MRG(acc1) MRG(acc2) MRG(acc3) MRG(den)
#undef MRG

  float rA = den.x > 0.f ? __builtin_amdgcn_rcpf(den.x) : 0.f;
  float rB = den.y > 0.f ? __builtin_amdgcn_rcpf(den.y) : 0.f;
  float rC = den.z > 0.f ? __builtin_amdgcn_rcpf(den.z) : 0.f;
  float rD = den.w > 0.f ? __builtin_amdgcn_rcpf(den.w) : 0.f;

  f32x4 p = el ? acc2 : acc0;
  f32x4 q = el ? acc3 : acc1;
  float rp = el ? rC : rA;
  float rq = el ? rD : rB;
  p *= splat4(rp); q *= splat4(rq);
#define ELU4(a) \
  a.x = (a.x > 0.f) ? a.x : (__expf(a.x) - 1.f); \
  a.y = (a.y > 0.f) ? a.y : (__expf(a.y) - 1.f); \
  a.z = (a.z > 0.f) ? a.z : (__expf(a.z) - 1.f); \
  a.w = (a.w > 0.f) ? a.w : (__expf(a.w) - 1.f);
  ELU4(p) ELU4(q)
#undef ELU4
  f32x4 s4 = p + q;
  s4.x += __shfl_xor(s4.x, 32);
  s4.y += __shfl_xor(s4.y, 32);
  s4.z += __shfl_xor(s4.z, 32);
  s4.w += __shfl_xor(s4.w, 32);
  f32x4 o = s4 * splat4(0.25f);

  if (el == 0) *(f32x4*)&out[(size_t)wid * D_H + dl * 4] = o;

  if (s_out) {
#pragma unroll
    for (int h = 0; h < HEADS; ++h) {
      const float* ah = &a_next[h * D_H + dl * 4];
      float p2 = o.x * ah[0] + o.y * ah[1] + o.z * ah[2] + o.w * ah[3];
#pragma unroll
      for (int off = 16; off; off >>= 1) p2 += __shfl_xor(p2, off);
      if (lane == 0) s_out[wid * HEADS + h] = p2;
    }
  }
}

// ---------------------------------------------------------------------------
extern "C" void kernel_launch(void* const* d_in, const int* in_sizes, int n_in,
                              void* d_out, int out_size, void* d_ws, size_t ws_size,
                              hipStream_t stream) {
  const float* h_user     = (const float*)d_in[0];
  const float* h_item     = (const float*)d_in[1];
  const float* w_user     = (const float*)d_in[2];
  const float* b_user     = (const float*)d_in[3];
  const float* w_item     = (const float*)d_in[4];
  const float* b_item     = (const float*)d_in[5];
  const float* a_user_src = (const float*)d_in[6];
  const float* a_user_dst = (const float*)d_in[7];
  const float* a_item_src = (const float*)d_in[8];
  const float* a_item_dst = (const float*)d_in[9];
  const int* i2u_src = (const int*)d_in[10];
  const int* i2u_dst = (const int*)d_in[11];
  const int* u2i_src = (const int*)d_in[12];
  const int* u2i_dst = (const int*)d_in[13];

  float* out_user = (float*)d_out;                       // hu_new (N_USER,128)
  float* out_item = out_user + (size_t)N_USER * D_H;     // hi_new (N_ITEM,128)

  // workspace layout
  float* hu      = (float*)d_ws;                         // (N_USER,128) 51.2MB
  float* hi      = hu + (size_t)N_USER * D_H;            // (N_ITEM,128)
  float* s_i_src = hi + (size_t)N_ITEM * D_H;            // (N_ITEM,4)
  float* s_i_dst = s_i_src + (size_t)N_ITEM * HEADS;     // (N_ITEM,4)
  float* s_u_dst = s_i_dst + (size_t)N_ITEM * HEADS;     // (N_USER,4)
  float* s_un    = s_u_dst + (size_t)N_USER * HEADS;     // (N_USER,4)
  int* user_rs = (int*)(s_un + (size_t)N_USER * HEADS);  // N_USER+1
  int* item_rs = user_rs + (N_USER + 1);                 // N_ITEM+1
  unsigned short* wtu_hi = (unsigned short*)
      (((uintptr_t)(item_rs + N_ITEM + 1) + 15) & ~(uintptr_t)15);
  unsigned short* wtu_lo = wtu_hi + (size_t)D_IN * D_H;
  unsigned short* wti_hi = wtu_lo + (size_t)D_IN * D_H;
  unsigned short* wti_lo = wti_hi + (size_t)D_IN * D_H;
  // hu is dead after scores_kernel -> alias edge weight buffer into it
  float* wbuf = hu;                                      // (E,4) 12.8MB

  // CSR offsets (edge-parallel run writes)
  hipLaunchKernelGGL(row_offsets_kernel, dim3((N_EDGE + 255) / 256), dim3(256), 0,
                     stream, i2u_dst, N_EDGE, user_rs, N_USER);
  hipLaunchKernelGGL(row_offsets_kernel, dim3((N_EDGE + 255) / 256), dim3(256), 0,
                     stream, u2i_dst, N_EDGE, item_rs, N_ITEM);

  // W prep + FUSED projections (one dispatch, 1173 blocks)
  hipLaunchKernelGGL(wt_prep_kernel, dim3(D_IN * D_H / 256), dim3(256), 0, stream,
                     w_user, wtu_hi, wtu_lo);
  hipLaunchKernelGGL(wt_prep_kernel, dim3(D_IN * D_H / 256), dim3(256), 0, stream,
                     w_item, wti_hi, wti_lo);
  const int nbu = (N_USER + 127) / 128;                  // 782
  const int nbi = (N_ITEM + 127) / 128;                  // 391
  hipLaunchKernelGGL(gemm_fused_kernel, dim3(nbu + nbi), dim3(256), 0, stream,
                     h_user, h_item, wtu_hi, wtu_lo, wti_hi, wti_lo,
                     b_user, b_item, hu, hi, nbu);

  // per-node attention scores
  hipLaunchKernelGGL(scores_kernel, dim3(N_ITEM / 4), dim3(256), 0, stream,
                     hi, N_ITEM, a_user_src, s_i_src, a_item_dst, s_i_dst);
  hipLaunchKernelGGL(scores_kernel, dim3(N_USER / 4), dim3(256), 0, stream,
                     hu, N_USER, a_user_dst, s_u_dst, (const float*)nullptr, (float*)nullptr);

  // ---- layer 1: items -> users ----
  hipLaunchKernelGGL(edge_w_kernel, dim3((N_EDGE + 255) / 256), dim3(256), 0, stream,
                     s_i_src, s_u_dst, i2u_src, i2u_dst, wbuf, N_EDGE);
  hipLaunchKernelGGL(attend_sum_kernel, dim3((N_USER + 3) / 4), dim3(256), 0, stream,
                     hi, wbuf, i2u_src, user_rs, out_user, N_USER,
                     a_item_src, s_un);

  // ---- layer 2: updated users -> items ----
  hipLaunchKernelGGL(edge_w_kernel, dim3((N_EDGE + 255) / 256), dim3(256), 0, stream,
                     s_un, s_i_dst, u2i_src, u2i_dst, wbuf, N_EDGE);
  hipLaunchKernelGGL(attend_sum_kernel, dim3((N_ITEM + 3) / 4), dim3(256), 0, stream,
                     out_user, wbuf, u2i_src, item_rs, out_item, N_ITEM,
                     (const float*)nullptr, (float*)nullptr);
}

// Round 13
// 311.620 us; speedup vs baseline: 1.3923x; 1.0497x over previous
//
#include <hip/hip_runtime.h>
#include <math.h>

#define N_USER 100000
#define N_ITEM 50000
#define N_EDGE 800000
#define D_IN 256
#define D_H 128
#define HEADS 4

typedef __attribute__((ext_vector_type(8))) short short8v;   // 8 bf16 (4 VGPR)
typedef __attribute__((ext_vector_type(4))) float f32x4;     // 4 fp32

__device__ __forceinline__ unsigned short f2bf(float x) {    // RNE f32->bf16
  unsigned u = __float_as_uint(x);
  return (unsigned short)((u + 0x7FFFu + ((u >> 16) & 1u)) >> 16);
}
__device__ __forceinline__ float bf2f(unsigned short h) {
  return __uint_as_float((unsigned)h << 16);
}
__device__ __forceinline__ f32x4 splat4(float x) { return (f32x4){x, x, x, x}; }

// ---------------------------------------------------------------------------
// CSR row offsets, edge-parallel run writes (each rs[i] written exactly once).
// ---------------------------------------------------------------------------
__global__ void row_offsets_kernel(const int* __restrict__ dst, int n_edge,
                                   int* __restrict__ rs, int n_dst) {
  int e = blockIdx.x * blockDim.x + threadIdx.x;
  if (e >= n_edge) return;
  int d = dst[e];
  int dprev = (e == 0) ? -1 : dst[e - 1];
  for (int i = dprev + 1; i <= d; ++i) rs[i] = e;
  if (e == n_edge - 1)
    for (int i = d + 1; i <= n_dst; ++i) rs[i] = n_edge;
}

// ---------------------------------------------------------------------------
// One-time W prep (RNE split): W[256][128] fp32 -> Wt_hi/Wt_lo[128][256] bf16,
// k permuted to MFMA slot order: pos(k) s.t. slot (kb,j) holds
// k = kb*4 + (j&3) + 16*(j>>2).
// ---------------------------------------------------------------------------
__global__ __launch_bounds__(256) void wt_prep_kernel(
    const float* __restrict__ W, unsigned short* __restrict__ WtHi,
    unsigned short* __restrict__ WtLo) {
  int tid = blockIdx.x * blockDim.x + threadIdx.x;
  if (tid >= D_IN * D_H) return;
  int n = tid & 127, k = tid >> 7;
  float x = W[(size_t)k * D_H + n];
  unsigned short h = f2bf(x);
  unsigned short l = f2bf(x - bf2f(h));
  int kk = k & 31, kbase = k & ~31;
  int pos = (kk < 16) ? ((kk >> 2) * 8 + (kk & 3))
                      : (((kk - 16) >> 2) * 8 + 4 + (kk & 3));
  WtHi[(size_t)n * D_IN + kbase + pos] = h;
  WtLo[(size_t)n * D_IN + kbase + pos] = l;
}

// ---------------------------------------------------------------------------
// Stage one K-step tile (A fp32 128x32 swizzled + B hi/lo 128x32 bf16) into
// LDS entirely via global_load_lds DMA (no dest VGPRs -> scheduler cannot
// serialize; B's register round-trip from r12 eliminated).
// ---------------------------------------------------------------------------
__device__ __forceinline__ void stage_tile(
    const float* __restrict__ A, const unsigned short* __restrict__ WtHi,
    const unsigned short* __restrict__ WtLo, int m0, int M, int k0,
    int wave, int lane, float* Af, unsigned short* Bh, unsigned short* Bl) {
  // A: wave fills rows wave*32..+31; lane l -> row base+(l>>3), unit l&7.
  // Source pre-swizzled: unit_src = (lane&7) ^ (row&7)  (m104/m173).
#pragma unroll
  for (int i = 0; i < 4; ++i) {
    int rloc = wave * 32 + i * 8 + (lane >> 3);
    int gr = m0 + rloc; if (gr >= M) gr = M - 1;       // clamp; rows never stored
    int u = (lane & 7) ^ (rloc & 7);
    const float* src = A + (size_t)gr * D_IN + k0 + u * 4;
    char* dstb = (char*)Af + (size_t)(wave * 32 + i * 8) * 128;  // wave-uniform
    __builtin_amdgcn_global_load_lds(
        (const __attribute__((address_space(1))) unsigned int*)src,
        (__attribute__((address_space(3))) unsigned int*)dstb, 16, 0, 0);
  }
  // B: row stride 64B; lane l -> row base+(l>>2), 16B unit l&3 (linear, no swz)
#pragma unroll
  for (int i = 0; i < 2; ++i) {
    int row = wave * 32 + i * 16 + (lane >> 2);
    int ch = lane & 3;
    const unsigned short* srch = WtHi + (size_t)row * D_IN + k0 + ch * 8;
    char* dsth = (char*)Bh + (size_t)(wave * 32 + i * 16) * 64;
    __builtin_amdgcn_global_load_lds(
        (const __attribute__((address_space(1))) unsigned int*)srch,
        (__attribute__((address_space(3))) unsigned int*)dsth, 16, 0, 0);
    const unsigned short* srcl = WtLo + (size_t)row * D_IN + k0 + ch * 8;
    char* dstl = (char*)Bl + (size_t)(wave * 32 + i * 16) * 64;
    __builtin_amdgcn_global_load_lds(
        (const __attribute__((address_space(1))) unsigned int*)srcl,
        (__attribute__((address_space(3))) unsigned int*)dstl, 16, 0, 0);
  }
}

// ---------------------------------------------------------------------------
// FUSED projections, 2-PHASE DOUBLE-BUFFERED (T3 minimum recipe):
//   STAGE(buf0); barrier;
//   loop t: STAGE(buf^1, t+1) -> COMPUTE(buf, t) -> barrier -> swap
// DMA for tile t+1 overlaps MFMA on tile t; the barrier's vmcnt(0) drain now
// sits AFTER a full compute phase instead of immediately after issue (r12's
// exposed-latency structure). All staging is DMA; zero register staging.
// C/D layout (verified m89): col = lane&15, row = (lane>>4)*4 + reg.
// ---------------------------------------------------------------------------
__global__ __launch_bounds__(256) void gemm_fused_kernel(
    const float* __restrict__ Au, const float* __restrict__ Ai,
    const unsigned short* __restrict__ WtUHi, const unsigned short* __restrict__ WtULo,
    const unsigned short* __restrict__ WtIHi, const unsigned short* __restrict__ WtILo,
    const float* __restrict__ bu, const float* __restrict__ bi,
    float* __restrict__ Cu, float* __restrict__ Ci, int nbu) {
  __shared__ float Af[2][128 * 32];                     // 2 x 16KB
  __shared__ unsigned short Bhs[2][128 * 32];           // 2 x 8KB
  __shared__ unsigned short Bls[2][128 * 32];           // 2 x 8KB  (total 64KB)
  const bool isU = (int)blockIdx.x < nbu;
  const float* A = isU ? Au : Ai;
  const unsigned short* WtHi = isU ? WtUHi : WtIHi;
  const unsigned short* WtLo = isU ? WtULo : WtILo;
  const float* bias = isU ? bu : bi;
  float* C = isU ? Cu : Ci;
  const int M = isU ? N_USER : N_ITEM;
  const int m0 = (isU ? (int)blockIdx.x : (int)blockIdx.x - nbu) * 128;

  const int t = threadIdx.x;
  const int wave = t >> 6, lane = t & 63;
  const int l15 = lane & 15, kb = lane >> 4;

  f32x4 acc[2][8];
#pragma unroll
  for (int mf = 0; mf < 2; ++mf)
#pragma unroll
    for (int nf = 0; nf < 8; ++nf) acc[mf][nf] = (f32x4){0.f, 0.f, 0.f, 0.f};

  stage_tile(A, WtHi, WtLo, m0, M, 0, wave, lane, Af[0], Bhs[0], Bls[0]);
  __syncthreads();                                     // tile 0 ready

#pragma unroll
  for (int ts = 0; ts < 8; ++ts) {
    const int cur = ts & 1;
    if (ts + 1 < 8)                                    // prefetch next tile
      stage_tile(A, WtHi, WtLo, m0, M, (ts + 1) * 32, wave, lane,
                 Af[cur ^ 1], Bhs[cur ^ 1], Bls[cur ^ 1]);

    // ---- A fragments: ds_read fp32 (swizzled) -> split to bf16 hi/lo ----
    short8v ah[2], al[2];
#pragma unroll
    for (int mf = 0; mf < 2; ++mf) {
      int row = wave * 32 + mf * 16 + l15;
      int u0 = kb ^ (row & 7);                  // slots j=0..3: k = kb*4+j
      int u1 = (kb + 4) ^ (row & 7);            // slots j=4..7: k = 16+kb*4+j-4
      float4 f0 = *(const float4*)((const char*)Af[cur] + (size_t)row * 128 + u0 * 16);
      float4 f1 = *(const float4*)((const char*)Af[cur] + (size_t)row * 128 + u1 * 16);
      const float e[8] = {f0.x, f0.y, f0.z, f0.w, f1.x, f1.y, f1.z, f1.w};
#pragma unroll
      for (int j = 0; j < 8; ++j) {
        unsigned short h = f2bf(e[j]);
        ah[mf][j] = (short)h;
        al[mf][j] = (short)f2bf(e[j] - bf2f(h));
      }
    }
#pragma unroll
    for (int nf = 0; nf < 8; ++nf) {
      short8v bh = *(const short8v*)((const char*)Bhs[cur] + (size_t)(nf * 16 + l15) * 64 + kb * 16);
      short8v bl = *(const short8v*)((const char*)Bls[cur] + (size_t)(nf * 16 + l15) * 64 + kb * 16);
#pragma unroll
      for (int mf = 0; mf < 2; ++mf) {
        acc[mf][nf] = __builtin_amdgcn_mfma_f32_16x16x32_bf16(ah[mf], bh, acc[mf][nf], 0, 0, 0);
        acc[mf][nf] = __builtin_amdgcn_mfma_f32_16x16x32_bf16(ah[mf], bl, acc[mf][nf], 0, 0, 0);
        acc[mf][nf] = __builtin_amdgcn_mfma_f32_16x16x32_bf16(al[mf], bh, acc[mf][nf], 0, 0, 0);
      }
    }
    __syncthreads();   // drains this iter's DMA (next tile) + all LDS reads
  }

#pragma unroll
  for (int nf = 0; nf < 8; ++nf) {
    float bv = bias[nf * 16 + l15];
#pragma unroll
    for (int mf = 0; mf < 2; ++mf) {
#pragma unroll
      for (int r = 0; r < 4; ++r) {
        int grow = m0 + wave * 32 + mf * 16 + kb * 4 + r;
        if (grow < M) C[(size_t)grow * D_H + nf * 16 + l15] = acc[mf][nf][r] + bv;
      }
    }
  }
}

// ---------------------------------------------------------------------------
// s[n,4] = C[n,128] @ a[4,128]^T  (one wave per row; optional second a)
// ---------------------------------------------------------------------------
__global__ __launch_bounds__(256) void scores_kernel(
    const float* __restrict__ C, int n,
    const float* __restrict__ a0, float* __restrict__ s0,
    const float* __restrict__ a1, float* __restrict__ s1) {
  int wid = (blockIdx.x * blockDim.x + threadIdx.x) >> 6;
  int lane = threadIdx.x & 63;
  if (wid >= n) return;
  float2 v = *(const float2*)&C[(size_t)wid * D_H + lane * 2];
#pragma unroll
  for (int h = 0; h < HEADS; ++h) {
    float p = v.x * a0[h * D_H + lane * 2] + v.y * a0[h * D_H + lane * 2 + 1];
#pragma unroll
    for (int off = 32; off; off >>= 1) p += __shfl_xor(p, off);
    if (lane == 0) s0[wid * HEADS + h] = p;
  }
  if (a1) {
#pragma unroll
    for (int h = 0; h < HEADS; ++h) {
      float p = v.x * a1[h * D_H + lane * 2] + v.y * a1[h * D_H + lane * 2 + 1];
#pragma unroll
      for (int off = 32; off; off >>= 1) p += __shfl_xor(p, off);
      if (lane == 0) s1[wid * HEADS + h] = p;
    }
  }
}

// ---------------------------------------------------------------------------
// Per-edge UNNORMALIZED weights w = exp(leaky_relu(s_src+s_dst)).
// ---------------------------------------------------------------------------
__global__ __launch_bounds__(256) void edge_w_kernel(
    const float* __restrict__ s_src, const float* __restrict__ s_dst,
    const int* __restrict__ src_idx, const int* __restrict__ dst_idx,
    float* __restrict__ wout, int n_edge) {
  int e = blockIdx.x * blockDim.x + threadIdx.x;
  if (e >= n_edge) return;
  int s = src_idx[e], d = dst_idx[e];
  f32x4 a = *(const f32x4*)&s_src[(size_t)s * HEADS];
  f32x4 b = *(const f32x4*)&s_dst[(size_t)d * HEADS];
  f32x4 v = a + b;
  v.x = (v.x >= 0.f) ? v.x : 0.2f * v.x;
  v.y = (v.y >= 0.f) ? v.y : 0.2f * v.y;
  v.z = (v.z >= 0.f) ? v.z : 0.2f * v.z;
  v.w = (v.w >= 0.f) ? v.w : 0.2f * v.w;
  f32x4 w = {__expf(v.x), __expf(v.y), __expf(v.z), __expf(v.w)};
  *(f32x4*)&wout[(size_t)e * HEADS] = w;
}

// ---------------------------------------------------------------------------
// Weighted gather-sum + in-loop denominator. One wave per dst;
// lanes = 2 edge-slots x 32 dim-groups (float4). Packed f32x4 math.
// Epilogue: rcp (not div); ELU split across half-waves.
// ---------------------------------------------------------------------------
__global__ __launch_bounds__(256) void attend_sum_kernel(
    const float* __restrict__ h_src, const float* __restrict__ w4,
    const int* __restrict__ src_idx, const int* __restrict__ rs,
    float* __restrict__ out, int n_dst,
    const float* __restrict__ a_next, float* __restrict__ s_out) {
  int wid = (blockIdx.x * blockDim.x + threadIdx.x) >> 6;
  int lane = threadIdx.x & 63;
  if (wid >= n_dst) return;
  const int el = lane >> 5;
  const int dl = lane & 31;
  int e0 = rs[wid], e1 = rs[wid + 1];

  f32x4 acc0 = {0, 0, 0, 0}, acc1 = acc0, acc2 = acc0, acc3 = acc0;
  f32x4 den = {0, 0, 0, 0};

  int base = e0;
  for (; base + 4 <= e1; base += 4) {
    int eA = base + el, eB = base + 2 + el;
    int sA = src_idx[eA], sB = src_idx[eB];
    f32x4 hA = *(const f32x4*)&h_src[(size_t)sA * D_H + dl * 4];
    f32x4 hB = *(const f32x4*)&h_src[(size_t)sB * D_H + dl * 4];
    f32x4 wA = *(const f32x4*)&w4[(size_t)eA * HEADS];
    f32x4 wB = *(const f32x4*)&w4[(size_t)eB * HEADS];
    den += wA; den += wB;
    acc0 = __builtin_elementwise_fma(splat4(wA.x), hA, acc0);
    acc1 = __builtin_elementwise_fma(splat4(wA.y), hA, acc1);
    acc2 = __builtin_elementwise_fma(splat4(wA.z), hA, acc2);
    acc3 = __builtin_elementwise_fma(splat4(wA.w), hA, acc3);
    acc0 = __builtin_elementwise_fma(splat4(wB.x), hB, acc0);
    acc1 = __builtin_elementwise_fma(splat4(wB.y), hB, acc1);
    acc2 = __builtin_elementwise_fma(splat4(wB.z), hB, acc2);
    acc3 = __builtin_elementwise_fma(splat4(wB.w), hB, acc3);
  }
  for (; base < e1; base += 2) {
    int e = base + el;
    bool valid = e < e1;
    int ec = valid ? e : e1 - 1;
    int s = src_idx[ec];
    f32x4 hv = *(const f32x4*)&h_src[(size_t)s * D_H + dl * 4];
    f32x4 wv = *(const f32x4*)&w4[(size_t)ec * HEADS];
    if (!valid) wv = (f32x4){0, 0, 0, 0};
    den += wv;
    acc0 = __builtin_elementwise_fma(splat4(wv.x), hv, acc0);
    acc1 = __builtin_elementwise_fma(splat4(wv.y), hv, acc1);
    acc2 = __builtin_elementwise_fma(splat4(wv.z), hv, acc2);
    acc3 = __builtin_elementwise_fma(splat4(wv.w), hv, acc3);
  }

#define MRG(a) \
  a.x += __shfl_xor(a.x, 32); a.y += __shfl_xor(a.y, 32); \
  a.z += __shfl_xor(a.z, 32); a.w += __shfl_xor(a.w, 32);
  MRG(acc0) MRG(acc1) MRG(acc2) MRG(acc3) MRG(den)
#undef MRG

  float rA = den.x > 0.f ? __builtin_amdgcn_rcpf(den.x) : 0.f;
  float rB = den.y > 0.f ? __builtin_amdgcn_rcpf(den.y) : 0.f;
  float rC = den.z > 0.f ? __builtin_amdgcn_rcpf(den.z) : 0.f;
  float rD = den.w > 0.f ? __builtin_amdgcn_rcpf(den.w) : 0.f;

  f32x4 p = el ? acc2 : acc0;
  f32x4 q = el ? acc3 : acc1;
  float rp = el ? rC : rA;
  float rq = el ? rD : rB;
  p *= splat4(rp); q *= splat4(rq);
#define ELU4(a) \
  a.x = (a.x > 0.f) ? a.x : (__expf(a.x) - 1.f); \
  a.y = (a.y > 0.f) ? a.y : (__expf(a.y) - 1.f); \
  a.z = (a.z > 0.f) ? a.z : (__expf(a.z) - 1.f); \
  a.w = (a.w > 0.f) ? a.w : (__expf(a.w) - 1.f);
  ELU4(p) ELU4(q)
#undef ELU4
  f32x4 s4 = p + q;
  s4.x += __shfl_xor(s4.x, 32);
  s4.y += __shfl_xor(s4.y, 32);
  s4.z += __shfl_xor(s4.z, 32);
  s4.w += __shfl_xor(s4.w, 32);
  f32x4 o = s4 * splat4(0.25f);

  if (el == 0) *(f32x4*)&out[(size_t)wid * D_H + dl * 4] = o;

  if (s_out) {
#pragma unroll
    for (int h = 0; h < HEADS; ++h) {
      const float* ah = &a_next[h * D_H + dl * 4];
      float p2 = o.x * ah[0] + o.y * ah[1] + o.z * ah[2] + o.w * ah[3];
#pragma unroll
      for (int off = 16; off; off >>= 1) p2 += __shfl_xor(p2, off);
      if (lane == 0) s_out[wid * HEADS + h] = p2;
    }
  }
}

// ---------------------------------------------------------------------------
extern "C" void kernel_launch(void* const* d_in, const int* in_sizes, int n_in,
                              void* d_out, int out_size, void* d_ws, size_t ws_size,
                              hipStream_t stream) {
  const float* h_user     = (const float*)d_in[0];
  const float* h_item     = (const float*)d_in[1];
  const float* w_user     = (const float*)d_in[2];
  const float* b_user     = (const float*)d_in[3];
  const float* w_item     = (const float*)d_in[4];
  const float* b_item     = (const float*)d_in[5];
  const float* a_user_src = (const float*)d_in[6];
  const float* a_user_dst = (const float*)d_in[7];
  const float* a_item_src = (const float*)d_in[8];
  const float* a_item_dst = (const float*)d_in[9];
  const int* i2u_src = (const int*)d_in[10];
  const int* i2u_dst = (const int*)d_in[11];
  const int* u2i_src = (const int*)d_in[12];
  const int* u2i_dst = (const int*)d_in[13];

  float* out_user = (float*)d_out;                       // hu_new (N_USER,128)
  float* out_item = out_user + (size_t)N_USER * D_H;     // hi_new (N_ITEM,128)

  // workspace layout
  float* hu      = (float*)d_ws;                         // (N_USER,128) 51.2MB
  float* hi      = hu + (size_t)N_USER * D_H;            // (N_ITEM,128)
  float* s_i_src = hi + (size_t)N_ITEM * D_H;            // (N_ITEM,4)
  float* s_i_dst = s_i_src + (size_t)N_ITEM * HEADS;     // (N_ITEM,4)
  float* s_u_dst = s_i_dst + (size_t)N_ITEM * HEADS;     // (N_USER,4)
  float* s_un    = s_u_dst + (size_t)N_USER * HEADS;     // (N_USER,4)
  int* user_rs = (int*)(s_un + (size_t)N_USER * HEADS);  // N_USER+1
  int* item_rs = user_rs + (N_USER + 1);                 // N_ITEM+1
  unsigned short* wtu_hi = (unsigned short*)
      (((uintptr_t)(item_rs + N_ITEM + 1) + 15) & ~(uintptr_t)15);
  unsigned short* wtu_lo = wtu_hi + (size_t)D_IN * D_H;
  unsigned short* wti_hi = wtu_lo + (size_t)D_IN * D_H;
  unsigned short* wti_lo = wti_hi + (size_t)D_IN * D_H;
  // hu is dead after scores_kernel -> alias edge weight buffer into it
  float* wbuf = hu;                                      // (E,4) 12.8MB

  // CSR offsets (edge-parallel run writes)
  hipLaunchKernelGGL(row_offsets_kernel, dim3((N_EDGE + 255) / 256), dim3(256), 0,
                     stream, i2u_dst, N_EDGE, user_rs, N_USER);
  hipLaunchKernelGGL(row_offsets_kernel, dim3((N_EDGE + 255) / 256), dim3(256), 0,
                     stream, u2i_dst, N_EDGE, item_rs, N_ITEM);

  // W prep + FUSED projections (2-phase dbuf, one dispatch, 1173 blocks)
  hipLaunchKernelGGL(wt_prep_kernel, dim3(D_IN * D_H / 256), dim3(256), 0, stream,
                     w_user, wtu_hi, wtu_lo);
  hipLaunchKernelGGL(wt_prep_kernel, dim3(D_IN * D_H / 256), dim3(256), 0, stream,
                     w_item, wti_hi, wti_lo);
  const int nbu = (N_USER + 127) / 128;                  // 782
  const int nbi = (N_ITEM + 127) / 128;                  // 391
  hipLaunchKernelGGL(gemm_fused_kernel, dim3(nbu + nbi), dim3(256), 0, stream,
                     h_user, h_item, wtu_hi, wtu_lo, wti_hi, wti_lo,
                     b_user, b_item, hu, hi, nbu);

  // per-node attention scores
  hipLaunchKernelGGL(scores_kernel, dim3(N_ITEM / 4), dim3(256), 0, stream,
                     hi, N_ITEM, a_user_src, s_i_src, a_item_dst, s_i_dst);
  hipLaunchKernelGGL(scores_kernel, dim3(N_USER / 4), dim3(256), 0, stream,
                     hu, N_USER, a_user_dst, s_u_dst, (const float*)nullptr, (float*)nullptr);

  // ---- layer 1: items -> users ----
  hipLaunchKernelGGL(edge_w_kernel, dim3((N_EDGE + 255) / 256), dim3(256), 0, stream,
                     s_i_src, s_u_dst, i2u_src, i2u_dst, wbuf, N_EDGE);
  hipLaunchKernelGGL(attend_sum_kernel, dim3((N_USER + 3) / 4), dim3(256), 0, stream,
                     hi, wbuf, i2u_src, user_rs, out_user, N_USER,
                     a_item_src, s_un);

  // ---- layer 2: updated users -> items ----
  hipLaunchKernelGGL(edge_w_kernel, dim3((N_EDGE + 255) / 256), dim3(256), 0, stream,
                     s_un, s_i_dst, u2i_src, u2i_dst, wbuf, N_EDGE);
  hipLaunchKernelGGL(attend_sum_kernel, dim3((N_ITEM + 3) / 4), dim3(256), 0, stream,
                     out_user, wbuf, u2i_src, item_rs, out_item, N_ITEM,
                     (const float*)nullptr, (float*)nullptr);
}